// Round 2
// baseline (370.368 us; speedup 1.0000x reference)
//
#include <hip/hip_runtime.h>

#define HH 512
#define WW 512
#define NB 8
#define NN 32

// ---------------------------------------------------------------------------
// Kernel A: per-row min/max column index of positive pixels in seg[...,1].
// One wave per row; float4 load = 2 (ch0,ch1) pixel pairs per lane per iter.
// ---------------------------------------------------------------------------
__global__ __launch_bounds__(256) void rowminmax_kernel(
    const float* __restrict__ seg, int* __restrict__ xmin, int* __restrict__ xmax) {
  int wv = threadIdx.x >> 6;
  int lane = threadIdx.x & 63;
  int g = blockIdx.x * 4 + wv;                 // global row id in [0, NB*HH)
  const float4* row = ((const float4*)seg) + (size_t)g * 256;  // 256 float4/row
  int mn = WW, mx = -1;
#pragma unroll
  for (int k = 0; k < 4; ++k) {
    int i = lane + k * 64;                     // float4 index: pixels 2i, 2i+1
    float4 v = row[i];
    if (v.y > 0.0f) { int w = 2 * i;     if (w < mn) mn = w; if (w > mx) mx = w; }
    if (v.w > 0.0f) { int w = 2 * i + 1; if (w < mn) mn = w; if (w > mx) mx = w; }
  }
  for (int off = 32; off; off >>= 1) {
    int omn = __shfl_down(mn, off);
    int omx = __shfl_down(mx, off);
    mn = min(mn, omn);
    mx = max(mx, omx);
  }
  if (lane == 0) { xmin[g] = mn; xmax[g] = mx; }
}

// ---------------------------------------------------------------------------
// Kernel B: per-batch weighted least-squares fit -> unit[h] = 3.25 / width[h].
// One block per batch, thread t == row t. Matches reference semantics.
// ---------------------------------------------------------------------------
__global__ __launch_bounds__(512) void fit_kernel(
    const int* __restrict__ xmin, const int* __restrict__ xmax,
    float* __restrict__ unit, float* __restrict__ unit2) {
  int b = blockIdx.x;
  int t = threadIdx.x;                         // row index
  int wv = t >> 6, lane = t & 63;
  __shared__ int s_scan[HH];
  __shared__ double s_red[8][8];
  __shared__ double s_fit[4];

  int xmn = xmin[b * HH + t];
  int xmx = xmax[b * HH + t];
  int valid = (xmx >= 0 && xmn != xmx) ? 1 : 0;
  s_scan[t] = valid;
  __syncthreads();
  for (int off = 1; off < HH; off <<= 1) {     // Hillis-Steele inclusive scan
    int add = (t >= off) ? s_scan[t - off] : 0;
    __syncthreads();
    s_scan[t] += add;
    __syncthreads();
  }
  int n_valid = s_scan[HH - 1];
  int rank = s_scan[t] - 1;
  int drop = (int)((float)n_valid * 0.15f);    // same f32 truncation as reference
  if (drop < 1) drop = 1;
  int keep = (valid && rank >= drop && rank < (n_valid - drop)) ? 1 : 0;

  double wg = (double)keep;
  double y  = (double)t;
  double xl = (double)xmn, xr = (double)xmx;
  double terms[7];
  terms[0] = wg;        terms[1] = wg * y;      terms[2] = wg * y * y;
  terms[3] = wg * xl;   terms[4] = wg * y * xl;
  terms[5] = wg * xr;   terms[6] = wg * y * xr;
#pragma unroll
  for (int i = 0; i < 7; ++i) {
    double v = terms[i];
    for (int off = 32; off; off >>= 1) v += __shfl_down(v, off);
    if (lane == 0) s_red[wv][i] = v;
  }
  __syncthreads();
  if (t == 0) {
    double S[7];
    for (int i = 0; i < 7; ++i) {
      double a = 0.0;
      for (int w2 = 0; w2 < 8; ++w2) a += s_red[w2][i];
      S[i] = a;
    }
    double Sw = S[0], Sy = S[1], Syy = S[2];
    double Sxl = S[3], Sxyl = S[4], Sxr = S[5], Sxyr = S[6];
    double det = Syy * Sw - Sy * Sy;
    double sl_l = 0, ic_l = 0, sl_r = 0, ic_r = 0;
    if (det > 0.0) {
      sl_l = (Sw * Sxyl - Sy * Sxl) / det;
      ic_l = (-Sy * Sxyl + Syy * Sxl) / det;
      sl_r = (Sw * Sxyr - Sy * Sxr) / det;
      ic_r = (-Sy * Sxyr + Syy * Sxr) / det;
    }
    s_fit[0] = sl_l; s_fit[1] = ic_l; s_fit[2] = sl_r; s_fit[3] = ic_r;
  }
  __syncthreads();
  double pl = y * s_fit[0] + s_fit[1];
  double pr = y * s_fit[2] + s_fit[3];
  double wdt = pr - pl;
  if (wdt < 1.0) wdt = 1.0;
  float u = (float)(3.25 / wdt);
  unit[b * HH + t]  = u;
  unit2[b * HH + t] = u * u;
}

// ---------------------------------------------------------------------------
// Kernel C: 256 MB streaming reduction, float4 loads, 4-deep unroll.
// Thread t = (row-phase r = t>>7, float4-col c = t&127); owns scalar columns
// 4c..4c+3 over rows h ≡ (h0 + 4k + r). Per-column partials recombined via
// an 8 KB LDS staging array; occ[h] via per-wave ballot (whole wave shares h).
// ---------------------------------------------------------------------------
__global__ __launch_bounds__(512) void reduce_kernel(
    const float4* __restrict__ pad4, const float* __restrict__ unit,
    const float* __restrict__ unit2, float* __restrict__ out) {
  int bn = blockIdx.x;                         // 0..255
  int b = bn >> 5;                             // N = 32
  int t = threadIdx.x;
  int wv = t >> 6, lane = t & 63;
  int r = t >> 7;                              // row phase 0..3 (wave-uniform)
  int c = t & 127;                             // float4 column index
  __shared__ float s_u[HH], s_u2[HH];
  __shared__ unsigned int s_occ[HH];
  __shared__ float s_colp[4][HH];              // per-phase column partials
  __shared__ float s_red[3][8];

  s_u[t]  = unit[b * HH + t];
  s_u2[t] = unit2[b * HH + t];
  s_occ[t] = 0u;
  __syncthreads();

  const float4* p = pad4 + (size_t)bn * (HH * 128);
  float cs0 = 0.f, cs1 = 0.f, cs2 = 0.f, cs3 = 0.f, instp = 0.f;
  for (int h0 = 0; h0 < HH; h0 += 16) {
    float4 v[4];
#pragma unroll
    for (int k = 0; k < 4; ++k)
      v[k] = p[(size_t)(h0 + 4 * k + r) * 128 + c];
#pragma unroll
    for (int k = 0; k < 4; ++k) {
      int h = h0 + 4 * k + r;
      float u = s_u[h], u2 = s_u2[h];
      cs0 = fmaf(u, v[k].x, cs0);
      cs1 = fmaf(u, v[k].y, cs1);
      cs2 = fmaf(u, v[k].z, cs2);
      cs3 = fmaf(u, v[k].w, cs3);
      instp = fmaf(u2, (v[k].x + v[k].y) + (v[k].z + v[k].w), instp);
      bool posq = (v[k].x > 0.5f) || (v[k].y > 0.5f) ||
                  (v[k].z > 0.5f) || (v[k].w > 0.5f);
      if (__ballot(posq)) { if (lane == 0) s_occ[h] = 1u; }  // benign same-value
    }
  }
  ((float4*)&s_colp[r][0])[c] = make_float4(cs0, cs1, cs2, cs3);
  __syncthreads();

  // thread t now acts as scalar column / row index w = t
  float col = s_colp[0][t] + s_colp[1][t] + s_colp[2][t] + s_colp[3][t];
  float vt = s_occ[t] ? s_u[t] : 0.0f;
  float si = instp, sv = vt, mc = col;
  for (int off = 32; off; off >>= 1) {
    si += __shfl_down(si, off);
    sv += __shfl_down(sv, off);
    float o = __shfl_down(mc, off);
    mc = fmaxf(mc, o);
  }
  if (lane == 0) { s_red[0][wv] = si; s_red[1][wv] = mc; s_red[2][wv] = sv; }
  __syncthreads();
  if (t == 0) {
    float a = 0.0f, m = -1e30f, vs = 0.0f;
    for (int i = 0; i < 8; ++i) {
      a += s_red[0][i];
      m = fmaxf(m, s_red[1][i]);
      vs += s_red[2][i];
    }
    out[bn * 3 + 0] = a;   // instance_size
    out[bn * 3 + 1] = m;   // horizontal_size
    out[bn * 3 + 2] = vs;  // vertical_size
  }
}

extern "C" void kernel_launch(void* const* d_in, const int* in_sizes, int n_in,
                              void* d_out, int out_size, void* d_ws, size_t ws_size,
                              hipStream_t stream) {
  const float* seg = (const float*)d_in[0];    // [B,H,W,2]
  const float* pad = (const float*)d_in[1];    // [B,N,H,W]
  float* out = (float*)d_out;                  // [B,N,3]
  char* ws = (char*)d_ws;
  int*   xmin  = (int*)(ws);                   // 16 KB
  int*   xmax  = (int*)(ws + 16 * 1024);       // 16 KB
  float* unit  = (float*)(ws + 32 * 1024);     // 16 KB
  float* unit2 = (float*)(ws + 48 * 1024);     // 16 KB

  rowminmax_kernel<<<NB * HH / 4, 256, 0, stream>>>(seg, xmin, xmax);
  fit_kernel<<<NB, 512, 0, stream>>>(xmin, xmax, unit, unit2);
  reduce_kernel<<<NB * NN, 512, 0, stream>>>((const float4*)pad, unit, unit2, out);
}